// Round 2
// baseline (639.667 us; speedup 1.0000x reference)
//
#include <hip/hip_runtime.h>

// Segment-mean aggregation:
//   feat_map [1, C=128, Hf=512, Wf=1024] f32, seg [Hf*Wf] i32 in [0,N=400)
//   out [N, C] f32 = per-segment mean of pixel features (0 for empty segments)
//
// R1 findings: atomicAdd(float) on LDS lowers to a CAS loop (dependent
// ds_read/ds_cmpst_rtn round-trips, ~820 cyc per iteration observed:
// VALUBusy 1.2%, 422 GB/s). Fix: unsafeAtomicAdd -> native ds_add_f32
// (no-return, no lgkm dependency). Also: 512 blocks (2 per CU, 32 waves/CU)
// and float4-vectorized finalize.

#define NSEG_MAX 400
#define CG 32            // channels per group (LDS table = CG*400*4 = 50 KB)
#define THREADS 1024

__device__ __forceinline__ void lds_fadd(float* p, float v) {
    // Native ds_add_f32 (no-return). Plain atomicAdd(float) takes the
    // safe-FP CAS path on AMD -> dependent LDS round-trips -> disaster.
    unsafeAtomicAdd(p, v);
}

__global__ __launch_bounds__(THREADS)
void seg_partial_kernel(const float* __restrict__ feat,
                        const int* __restrict__ seg,
                        float* __restrict__ ws_sums,   // [C][B][N]
                        float* __restrict__ ws_cnt,    // [B][N]
                        long P, int N, int B, int kIters)
{
    __shared__ float s_sum[CG * NSEG_MAX];   // [dc][400]; random seg spreads banks
    __shared__ int   s_cnt[NSEG_MAX];

    const int tid = threadIdx.x;
    const int b   = blockIdx.x;     // pixel-chunk index
    const int g   = blockIdx.y;     // channel-group index
    const int c0  = g * CG;

    for (int i = tid; i < CG * NSEG_MAX; i += THREADS) s_sum[i] = 0.f;
    if (tid < NSEG_MAX) s_cnt[tid] = 0;
    __syncthreads();

    const long pixPerBlock = (long)kIters * (THREADS * 4);
    const long pbase = (long)b * pixPerBlock;

    for (int k = 0; k < kIters; ++k) {
        const long p = pbase + (long)k * (THREADS * 4) + (long)tid * 4;
        const int4 sq = *(const int4*)(seg + p);
        if (g == 0) {   // counts are channel-independent: only group 0 does them
            atomicAdd(&s_cnt[sq.x], 1);   // int atomic: native
            atomicAdd(&s_cnt[sq.y], 1);
            atomicAdd(&s_cnt[sq.z], 1);
            atomicAdd(&s_cnt[sq.w], 1);
        }
        #pragma unroll 8
        for (int dc = 0; dc < CG; ++dc) {
            const float4 v = *(const float4*)(feat + (long)(c0 + dc) * P + p);
            lds_fadd(&s_sum[dc * NSEG_MAX + sq.x], v.x);
            lds_fadd(&s_sum[dc * NSEG_MAX + sq.y], v.y);
            lds_fadd(&s_sum[dc * NSEG_MAX + sq.z], v.z);
            lds_fadd(&s_sum[dc * NSEG_MAX + sq.w], v.w);
        }
    }
    __syncthreads();

    // Flush LDS table -> global partials (plain coalesced stores).
    for (int i = tid; i < CG * N; i += THREADS) {
        const int dc = i / N;
        const int s  = i - dc * N;
        ws_sums[((long)(c0 + dc) * B + b) * N + s] = s_sum[dc * NSEG_MAX + s];
    }
    if (g == 0) {
        for (int s = tid; s < N; s += THREADS)
            ws_cnt[(long)b * N + s] = (float)s_cnt[s];
    }
}

// One thread per (c, 4 consecutive s): float4 partial reads, B-deep sum.
__global__ __launch_bounds__(256)
void seg_finalize_kernel(const float* __restrict__ ws_sums,
                         const float* __restrict__ ws_cnt,
                         float* __restrict__ out,
                         int N, int C, int B)
{
    const int t = blockIdx.x * 256 + threadIdx.x;
    const int nQuad = N / 4;                 // N=400 -> 100
    if (t >= C * nQuad) return;
    const int c  = t / nQuad;
    const int s4 = (t - c * nQuad) * 4;

    float4 sum = make_float4(0.f, 0.f, 0.f, 0.f);
    float4 cnt = make_float4(0.f, 0.f, 0.f, 0.f);
    const float* ps = ws_sums + (long)c * B * N + s4;
    const float* pc = ws_cnt + s4;
    #pragma unroll 8
    for (int b = 0; b < B; ++b) {
        const float4 v = *(const float4*)(ps + (long)b * N);
        const float4 w = *(const float4*)(pc + (long)b * N);
        sum.x += v.x; sum.y += v.y; sum.z += v.z; sum.w += v.w;
        cnt.x += w.x; cnt.y += w.y; cnt.z += w.z; cnt.w += w.w;
    }
    out[(s4 + 0) * C + c] = cnt.x > 0.f ? sum.x / cnt.x : 0.f;
    out[(s4 + 1) * C + c] = cnt.y > 0.f ? sum.y / cnt.y : 0.f;
    out[(s4 + 2) * C + c] = cnt.z > 0.f ? sum.z / cnt.z : 0.f;
    out[(s4 + 3) * C + c] = cnt.w > 0.f ? sum.w / cnt.w : 0.f;
}

extern "C" void kernel_launch(void* const* d_in, const int* in_sizes, int n_in,
                              void* d_out, int out_size, void* d_ws, size_t ws_size,
                              hipStream_t stream)
{
    const float* feat = (const float*)d_in[0];
    const int*   seg  = (const int*)d_in[1];
    float*       out  = (float*)d_out;

    const long P = in_sizes[1];             // 512*1024 = 524288 pixels
    const int  C = (int)(in_sizes[0] / P);  // 128
    const int  N = out_size / C;            // 400

    // B=128 -> grid 512 blocks (2 blocks/CU, 32 waves/CU); ws = 26.4 MB.
    const size_t perB = (size_t)(C + 1) * (size_t)N * sizeof(float);
    int B = 128;
    while (B > 1 && ((size_t)B * perB > ws_size ||
                     (P % ((long)B * THREADS * 4)) != 0))
        B >>= 1;
    const int kIters = (int)(P / ((long)B * THREADS * 4));

    float* ws_sums = (float*)d_ws;                       // C*B*N floats
    float* ws_cnt  = ws_sums + (size_t)C * B * N;        // B*N floats

    dim3 grid1(B, C / CG);
    seg_partial_kernel<<<grid1, dim3(THREADS), 0, stream>>>(
        feat, seg, ws_sums, ws_cnt, P, N, B, kIters);

    const int total = C * (N / 4);
    seg_finalize_kernel<<<(total + 255) / 256, 256, 0, stream>>>(
        ws_sums, ws_cnt, out, N, C, B);
}

// Round 3
// 612.077 us; speedup vs baseline: 1.0451x; 1.0451x over previous
//
#include <hip/hip_runtime.h>

// Segment-mean aggregation:
//   feat_map [1, C=128, 512, 1024] f32, seg [P=524288] i32 in [0,N=400)
//   out [N, C] f32 = per-segment mean (0 for empty segments)
//
// R2 post-mortem: bottleneck is VMEM latency serialization (~800 cyc/wave-load
// CU-wide; VALUBusy 2%, no bank conflicts; finalize kernel equally slow with
// zero LDS atomics). R3: per-block CONTIGUOUS streaming (block = one channel x
// one pixel window), explicit 2-deep load pipeline (2 loads in flight/wave),
// tiny 400-float LDS table, flush via native global fp32 atomics into a
// 206 KB L2-resident accumulator. LDS-atomic rate per CU unchanged -> clean
// discriminating experiment vs the LDS-atomic-throughput hypothesis.

#define NSEG 400
#define THREADS 256

__global__ __launch_bounds__(256)
void zero_kernel(float* __restrict__ p, int n)
{
    const int i = blockIdx.x * 256 + threadIdx.x;
    if (i < n) p[i] = 0.f;
}

__global__ __launch_bounds__(THREADS, 8)   // 8 waves/SIMD = 32 waves/CU
void seg_partial_kernel(const float* __restrict__ feat,
                        const int* __restrict__ seg,
                        float* __restrict__ acc,    // [C][N] global accum
                        float* __restrict__ cnt,    // [N]
                        long P, int N, int kIters)
{
    __shared__ float s_sum[NSEG];
    __shared__ int   s_cnt[NSEG];

    const int tid = threadIdx.x;
    const int c   = blockIdx.x;       // channel
    const int w   = blockIdx.y;       // pixel window
    const bool doCnt = (c == 0);      // counts are channel-independent

    for (int i = tid; i < NSEG; i += THREADS) { s_sum[i] = 0.f; s_cnt[i] = 0; }
    __syncthreads();

    // Contiguous stream: this block covers pixels [pbase, pbase + kIters*1024)
    const long pbase = (long)w * kIters * (THREADS * 4);
    const float* fp = feat + (long)c * P + pbase + (long)tid * 4;
    const int*   sp = seg  + pbase + (long)tid * 4;

    // 2-deep software pipeline: keep next iteration's loads in flight while
    // scattering this iteration's values into LDS.
    int4   sqA = *(const int4*)(sp);
    float4 vA  = *(const float4*)(fp);

    for (int k = 0; k < kIters; ++k) {
        int4 sqB; float4 vB;
        if (k + 1 < kIters) {
            const long off = (long)(k + 1) * (THREADS * 4);
            sqB = *(const int4*)(sp + off);
            vB  = *(const float4*)(fp + off);
        }
        unsafeAtomicAdd(&s_sum[sqA.x], vA.x);   // native ds_add_f32
        unsafeAtomicAdd(&s_sum[sqA.y], vA.y);
        unsafeAtomicAdd(&s_sum[sqA.z], vA.z);
        unsafeAtomicAdd(&s_sum[sqA.w], vA.w);
        if (doCnt) {
            atomicAdd(&s_cnt[sqA.x], 1);        // native ds_add_u32
            atomicAdd(&s_cnt[sqA.y], 1);
            atomicAdd(&s_cnt[sqA.z], 1);
            atomicAdd(&s_cnt[sqA.w], 1);
        }
        sqA = sqB; vA = vB;
    }
    __syncthreads();

    // Flush: 16-way contention max per address, 206 KB L2-resident target.
    for (int s = tid; s < N; s += THREADS) {
        unsafeAtomicAdd(&acc[(long)c * N + s], s_sum[s]);
        if (doCnt) unsafeAtomicAdd(&cnt[s], (float)s_cnt[s]);
    }
}

__global__ __launch_bounds__(256)
void seg_finalize_kernel(const float* __restrict__ acc,
                         const float* __restrict__ cnt,
                         float* __restrict__ out, int N, int C)
{
    const int t = blockIdx.x * 256 + threadIdx.x;
    if (t >= N * C) return;
    const int s = t / C;
    const int c = t - s * C;
    const float ct = cnt[s];                       // broadcast within runs
    out[t] = (ct > 0.f) ? acc[(long)c * N + s] / ct : 0.f;   // coalesced store
}

extern "C" void kernel_launch(void* const* d_in, const int* in_sizes, int n_in,
                              void* d_out, int out_size, void* d_ws, size_t ws_size,
                              hipStream_t stream)
{
    const float* feat = (const float*)d_in[0];
    const int*   seg  = (const int*)d_in[1];
    float*       out  = (float*)d_out;

    const long P = in_sizes[1];             // 524288
    const int  C = (int)(in_sizes[0] / P);  // 128
    const int  N = out_size / C;            // 400

    int W = 16;                             // pixel windows -> grid C x W
    while (W > 1 && (P % ((long)W * THREADS * 4)) != 0) W >>= 1;
    const int kIters = (int)(P / ((long)W * THREADS * 4));   // 32

    float* acc = (float*)d_ws;              // C*N floats
    float* cnt = acc + (size_t)C * N;       // N floats

    const int nz = C * N + N;
    zero_kernel<<<(nz + 255) / 256, 256, 0, stream>>>(acc, nz);

    seg_partial_kernel<<<dim3(C, W), dim3(THREADS), 0, stream>>>(
        feat, seg, acc, cnt, P, N, kIters);

    seg_finalize_kernel<<<(N * C + 255) / 256, 256, 0, stream>>>(
        acc, cnt, out, N, C);
}